// Round 2
// baseline (401.396 us; speedup 1.0000x reference)
//
#include <hip/hip_runtime.h>
#include <cstdint>
#include <cstddef>

typedef __attribute__((ext_vector_type(8))) short bf16x8;
typedef __attribute__((ext_vector_type(4))) float f32x4;
typedef __attribute__((ext_vector_type(4))) int i32x4;

__device__ inline unsigned short cvt_bf16_rne(float f) {
    unsigned u = __builtin_bit_cast(unsigned, f);
    u = (u + 0x7FFFu + ((u >> 16) & 1u)) >> 16;
    return (unsigned short)u;
}
__device__ inline float bf16_to_f32(unsigned short s) {
    return __builtin_bit_cast(float, (unsigned)s << 16);
}

// ---------------------------------------------------------------------------
// Detect x_mask storage format: 0 = int32 {0,1}, 1 = bytes {0,1}, 2 = float32.
__global__ void detect_mask_kernel(const unsigned int* m, int* flag) {
    int i = blockIdx.x * blockDim.x + threadIdx.x;  // 8192 threads
    int f = 0;
    #pragma unroll
    for (int k = 0; k < 4; ++k) {
        unsigned int v = m[i * 4 + k];
        if (v == 0x3F800000u) f |= 2;
        else if (v > 1u) f |= 1;
    }
    if (f) atomicOr(flag, f);
}

// ---------------------------------------------------------------------------
// Pack mid-layer weights (layers 1..3) into MFMA A-fragment lane order (bf16).
// grid dim3(9, 4, 3) [tap, action, layer], 512 threads.
// Block (0,0,0) also clears the mask-format flag (detect runs after us).
__global__ void apack_all_kernel(const float* __restrict__ cw1,
                                 const float* __restrict__ cw2,
                                 const float* __restrict__ cw3,
                                 char* __restrict__ apack,
                                 int* __restrict__ flag) {
    int t = threadIdx.x;
    int tap = blockIdx.x, a = blockIdx.y, lz = blockIdx.z;
    if (tap == 0 && a == 0 && lz == 0 && t == 0) *flag = 0;
    const float* cw = (lz == 0) ? cw1 : (lz == 1 ? cw2 : cw3);
    char* outp = apack + (size_t)lz * 294912;
    int ks = t >> 8, mf = (t >> 6) & 3, lane = t & 63;
    int n = lane & 15, q = lane >> 4;
    int co = mf * 16 + n;
    int ci0 = ks * 32 + q * 8;
    unsigned d[4];
    #pragma unroll
    for (int jj = 0; jj < 4; ++jj) {
        unsigned short h0 = cvt_bf16_rne(cw[((size_t)(a * 64 + co) * 64 + ci0 + 2 * jj + 0) * 9 + tap]);
        unsigned short h1 = cvt_bf16_rne(cw[((size_t)(a * 64 + co) * 64 + ci0 + 2 * jj + 1) * 9 + tap]);
        d[jj] = (unsigned)h0 | ((unsigned)h1 << 16);
    }
    *(i32x4*)(outp + ((((size_t)(a * 9 + tap) * 2 + ks) * 4 + mf) * 1024 + lane * 16)) =
        *(i32x4*)d;
}

// ---------------------------------------------------------------------------
// Shared MFMA body for the mid layers: consumes the staged 10x34 halo tile in
// lds4, runs the 64->64 implicit GEMM, ReLU, stores bf16 act tile.
__device__ __forceinline__ void conv_mid_body(const i32x4* lds4,
                                              const char* __restrict__ apack_l,
                                              const float* __restrict__ cb,
                                              unsigned short* __restrict__ act_out,
                                              int a, int r0, int c0, int tid) {
    int lane = tid & 63, wv = tid >> 6;
    int n = lane & 15, q = lane >> 4;

    f32x4 acc[4][4];
    #pragma unroll
    for (int mf = 0; mf < 4; ++mf) {
        f32x4 bb = *(const f32x4*)(cb + a * 64 + mf * 16 + q * 4);
        #pragma unroll
        for (int nf = 0; nf < 4; ++nf) acc[mf][nf] = bb;
    }

    int base_nf[4];
    #pragma unroll
    for (int nf = 0; nf < 4; ++nf) {
        int orl = wv * 2 + (nf >> 1);
        int ocl = ((nf & 1) << 4) + n;
        base_nf[nf] = (orl * 34 + ocl) * 9 + q;  // i32x4 index at ty=tx=0,ks=0
    }
    const char* ap = apack_l + (size_t)a * 9 * 8192 + lane * 16;

    #pragma unroll
    for (int tap = 0; tap < 9; ++tap) {
        const int ty = tap / 3, tx = tap - ty * 3;
        const int toff = (ty * 34 + tx) * 9;
        #pragma unroll
        for (int ks = 0; ks < 2; ++ks) {
            bf16x8 Af[4], Bf[4];
            #pragma unroll
            for (int mf = 0; mf < 4; ++mf)
                Af[mf] = __builtin_bit_cast(bf16x8,
                    *(const i32x4*)(ap + (((tap * 2 + ks) * 4 + mf) << 10)));
            #pragma unroll
            for (int nf = 0; nf < 4; ++nf)
                Bf[nf] = __builtin_bit_cast(bf16x8, lds4[base_nf[nf] + toff + ks * 4]);
            #pragma unroll
            for (int mf = 0; mf < 4; ++mf)
                #pragma unroll
                for (int nf = 0; nf < 4; ++nf)
                    acc[mf][nf] = __builtin_amdgcn_mfma_f32_16x16x32_bf16(
                        Af[mf], Bf[nf], acc[mf][nf], 0, 0, 0);
        }
    }

    #pragma unroll
    for (int nf = 0; nf < 4; ++nf) {
        int grow = r0 + wv * 2 + (nf >> 1);
        int gcol = c0 + ((nf & 1) << 4) + n;
        char* ob = (char*)act_out + (((size_t)(a << 16) + (grow << 8) + gcol) << 7) + q * 8;
        #pragma unroll
        for (int mf = 0; mf < 4; ++mf) {
            f32x4 v = acc[mf][nf];
            unsigned d0 = (unsigned)cvt_bf16_rne(fmaxf(v.x, 0.0f))
                        | ((unsigned)cvt_bf16_rne(fmaxf(v.y, 0.0f)) << 16);
            unsigned d1 = (unsigned)cvt_bf16_rne(fmaxf(v.z, 0.0f))
                        | ((unsigned)cvt_bf16_rne(fmaxf(v.w, 0.0f)) << 16);
            uint2 st; st.x = d0; st.y = d1;
            *(uint2*)(ob + mf * 32) = st;
        }
    }
}

// ---------------------------------------------------------------------------
// Mid layers 2,3: stage bf16 act tile from global, then MFMA body.
// grid dim3(8, 32, 4), 256 threads.
__global__ __launch_bounds__(256, 3)
void conv_mid_mfma(const unsigned short* __restrict__ act_in,
                   const char* __restrict__ apack_l,
                   const float* __restrict__ cb,
                   unsigned short* __restrict__ act_out) {
    __shared__ i32x4 lds4[340 * 9];
    int tid = threadIdx.x;
    int a = blockIdx.z;
    int r0 = blockIdx.y * 8, c0 = blockIdx.x * 32;
    const char* actb = (const char*)act_in;

    for (int s = tid; s < 2720; s += 256) {
        int px = s >> 3, o = s & 7;
        int prow = px / 34, pcol = px - prow * 34;
        int grow = r0 - 1 + prow, gcol = c0 - 1 + pcol;
        i32x4 v = {0, 0, 0, 0};
        if ((unsigned)grow < 256u && (unsigned)gcol < 256u)
            v = *(const i32x4*)(actb + (((size_t)(a << 16) + (grow << 8) + gcol) << 7) + (o << 4));
        lds4[px * 9 + o] = v;
    }
    __syncthreads();
    conv_mid_body(lds4, apack_l, cb, act_out, a, r0, c0, tid);
}

// ---------------------------------------------------------------------------
// Layer 1 with layer 0 fused: stage a 12x36 fp32 img tile, compute the 1->64
// first conv + ReLU on the fly directly into lds4 (identical FMA order to the
// old conv_first_kernel => bit-identical), then the same MFMA body.
// grid dim3(8, 32, 4), 256 threads.
__global__ __launch_bounds__(256, 3)
void conv_mid_fused0(const float* __restrict__ img,
                     const float* __restrict__ cw0,
                     const float* __restrict__ cb0,
                     const char* __restrict__ apack_l,
                     const float* __restrict__ cb,
                     unsigned short* __restrict__ act_out) {
    __shared__ i32x4 lds4[340 * 9];
    __shared__ float img_s[12 * 36];
    int tid = threadIdx.x;
    int a = blockIdx.z;
    int r0 = blockIdx.y * 8, c0 = blockIdx.x * 32;

    for (int s = tid; s < 432; s += 256) {
        int ir = s / 36, ic = s - ir * 36;
        int gr = r0 - 2 + ir, gc = c0 - 2 + ic;
        img_s[s] = ((unsigned)gr < 256u && (unsigned)gc < 256u) ? img[gr * 256 + gc] : 0.0f;
    }
    __syncthreads();

    // Each thread keeps a fixed ci-octet o across its staging units.
    int o = tid & 7;
    float wr[8][9], br[8];
    #pragma unroll
    for (int j = 0; j < 8; ++j) {
        const float* wp = cw0 + ((size_t)a * 64 + o * 8 + j) * 9;
        #pragma unroll
        for (int t = 0; t < 9; ++t) wr[j][t] = wp[t];
        br[j] = cb0[a * 64 + o * 8 + j];
    }

    for (int s = tid; s < 2720; s += 256) {
        int px = s >> 3;
        int prow = px / 34, pcol = px - prow * 34;
        int grow = r0 - 1 + prow, gcol = c0 - 1 + pcol;
        i32x4 v = {0, 0, 0, 0};
        if ((unsigned)grow < 256u && (unsigned)gcol < 256u) {
            float accv[8];
            #pragma unroll
            for (int j = 0; j < 8; ++j) accv[j] = br[j];
            #pragma unroll
            for (int dy = 0; dy < 3; ++dy)
                #pragma unroll
                for (int dx = 0; dx < 3; ++dx) {
                    float iv = img_s[(prow + dy) * 36 + (pcol + dx)];
                    #pragma unroll
                    for (int j = 0; j < 8; ++j)
                        accv[j] = fmaf(wr[j][dy * 3 + dx], iv, accv[j]);
                }
            unsigned d[4];
            #pragma unroll
            for (int jj = 0; jj < 4; ++jj) {
                unsigned short h0 = cvt_bf16_rne(fmaxf(accv[2 * jj + 0], 0.0f));
                unsigned short h1 = cvt_bf16_rne(fmaxf(accv[2 * jj + 1], 0.0f));
                d[jj] = (unsigned)h0 | ((unsigned)h1 << 16);
            }
            v = *(i32x4*)d;
        }
        lds4[px * 9 + o] = v;
    }
    __syncthreads();
    conv_mid_body(lds4, apack_l, cb, act_out, a, r0, c0, tid);
}

// ---------------------------------------------------------------------------
// Layer 4: 64 -> 1, no ReLU, fp32 out W_a[a][256][256].
__global__ void conv_last_kernel(const unsigned short* __restrict__ act,
                                 const float* __restrict__ cw4,
                                 const float* __restrict__ cb4,
                                 float* __restrict__ W_a) {
    int y = blockIdx.x, a = blockIdx.y;
    int tid = threadIdx.x;
    int lane = tid & 63, wv = tid >> 6;
    int o = lane & 7, pl = lane >> 3;
    float wr[8][9];
    #pragma unroll
    for (int j = 0; j < 8; ++j) {
        const float* wp = cw4 + ((size_t)a * 64 + o * 8 + j) * 9;
        #pragma unroll
        for (int t = 0; t < 9; ++t) wr[j][t] = wp[t];
    }
    const char* actb = (const char*)act;
    float bias = cb4[a];
    for (int i = 0; i < 8; ++i) {
        int x = i * 32 + wv * 8 + pl;
        float p = 0.0f;
        #pragma unroll
        for (int ty = 0; ty < 3; ++ty) {
            int py = y + ty - 1;
            #pragma unroll
            for (int tx = 0; tx < 3; ++tx) {
                int px = x + tx - 1;
                if ((unsigned)py < 256u && (unsigned)px < 256u) {
                    i32x4 v = *(const i32x4*)(actb +
                        (((size_t)(a << 16) + (py << 8) + px) << 7) + (o << 4));
                    const unsigned* dv = (const unsigned*)&v;
                    #pragma unroll
                    for (int j = 0; j < 8; ++j) {
                        unsigned d = dv[j >> 1];
                        unsigned short us = (j & 1) ? (unsigned short)(d >> 16)
                                                    : (unsigned short)(d & 0xffffu);
                        p = fmaf(bf16_to_f32(us), wr[j][ty * 3 + tx], p);
                    }
                }
            }
        }
        p += __shfl_xor(p, 1, 64);
        p += __shfl_xor(p, 2, 64);
        p += __shfl_xor(p, 4, 64);
        if (o == 0) W_a[(size_t)(a << 16) + (y << 8) + x] = p + bias;
    }
}

// ---------------------------------------------------------------------------
// Wy[b,x] = sum_h y[b,h] * W_a[actions[b], h, x].
// 1024 threads: 4 partial-threads per x column (hq = t&3 handles h = i*4+hq),
// 4x shorter serial dependence than 1-thread-per-x; 2-shuffle finish.
__global__ void wy_kernel(const float* __restrict__ yv,
                          const int* __restrict__ actions,
                          const float* __restrict__ W_a,
                          float* __restrict__ Wy) {
    int b = blockIdx.x, t = threadIdx.x;
    int x = t >> 2, hq = t & 3;
    int a = actions[b];
    const float* Wp = W_a + (size_t)a * 65536;
    const float* yb = yv + b * 256;
    float acc = 0.0f;
    #pragma unroll 8
    for (int i = 0; i < 64; ++i) {
        int h = i * 4 + hq;
        acc = fmaf(yb[h], Wp[(size_t)h * 256 + x], acc);
    }
    acc += __shfl_xor(acc, 1, 64);
    acc += __shfl_xor(acc, 2, 64);
    if (hq == 0) Wy[b * 256 + x] = acc;
}

// ---------------------------------------------------------------------------
// Logits: LDS partial-transpose reduction (no dependent shuffle chains).
// grid (8, 32), 256 threads. Per wave pass: 64 rows; lane dots 4 elems,
// one shfl_xor(16) pre-reduce -> 32 partials/row -> LDS; then lane L sums
// row L contiguously (8x ds_read_b128) and does coalesced mask+store.
__global__ void logits_kernel(const float* __restrict__ xv,
                              const void* __restrict__ mask,
                              const int* __restrict__ flag,
                              const float* __restrict__ Wy,
                              float* __restrict__ out) {
    __shared__ float part[4][64][36];   // 36-float row stride: 16B-aligned rows
    int tid = threadIdx.x, lane = tid & 63, w = tid >> 6;
    int b = blockIdx.y;
    int fl = *flag;
    float4 wy4 = *(const float4*)(Wy + b * 256 + lane * 4);
    const float* xb = xv + (size_t)b * 4096 * 256;
    int slot = (lane & 15) | ((lane >> 5) << 4);   // 0..31, unique on active lanes
    bool wr = (lane & 16) == 0;
    float ninf = -__builtin_inff();

    #pragma unroll
    for (int pass = 0; pass < 2; ++pass) {
        int rowbase = blockIdx.x * 512 + pass * 256 + w * 64;
        #pragma unroll 4
        for (int li = 0; li < 64; ++li) {
            const float4 x4 = *(const float4*)(xb + (size_t)(rowbase + li) * 256 + lane * 4);
            float p = x4.x * wy4.x + x4.y * wy4.y + x4.z * wy4.z + x4.w * wy4.w;
            p += __shfl_xor(p, 16, 64);
            if (wr) part[w][li][slot] = p;
        }
        // Per-wave private LDS region; compiler inserts the lgkm wait for the
        // read-after-write below (same array, cannot prove non-aliasing).
        float s = 0.0f;
        #pragma unroll
        for (int j = 0; j < 8; ++j) {
            f32x4 v4 = *(const f32x4*)&part[w][lane][j * 4];
            s += (v4.x + v4.y) + (v4.z + v4.w);
        }
        int r = rowbase + lane;
        size_t mi = (size_t)b * 4096 + r;
        bool msk;
        if (fl & 2)      msk = ((const float*)mask)[mi] != 0.0f;
        else if (fl & 1) msk = ((const unsigned char*)mask)[mi] != 0;
        else             msk = ((const int*)mask)[mi] != 0;
        out[mi] = msk ? ninf : s;
        __syncthreads();   // reuse LDS region next pass
    }
}

// ---------------------------------------------------------------------------
__global__ void softmax_kernel(float* __restrict__ out) {
    int b = blockIdx.x, tid = threadIdx.x;
    int lane = tid & 63, wid = tid >> 6;
    float* row = out + (size_t)b * 4096;
    float v[4];
    float m = -__builtin_inff();
    #pragma unroll
    for (int i = 0; i < 4; ++i) { v[i] = row[tid + i * 1024]; m = fmaxf(m, v[i]); }
    #pragma unroll
    for (int off = 32; off > 0; off >>= 1) m = fmaxf(m, __shfl_xor(m, off, 64));
    __shared__ float redm[16];
    __shared__ float reds[16];
    if (lane == 0) redm[wid] = m;
    __syncthreads();
    float M = redm[0];
    #pragma unroll
    for (int j = 1; j < 16; ++j) M = fmaxf(M, redm[j]);
    float s = 0.0f;
    #pragma unroll
    for (int i = 0; i < 4; ++i) { v[i] = expf(v[i] - M); s += v[i]; }
    #pragma unroll
    for (int off = 32; off > 0; off >>= 1) s += __shfl_xor(s, off, 64);
    if (lane == 0) reds[wid] = s;
    __syncthreads();
    float S = 0.0f;
    #pragma unroll
    for (int j = 0; j < 16; ++j) S += reds[j];
    float inv = 1.0f / S;
    #pragma unroll
    for (int i = 0; i < 4; ++i) row[tid + i * 1024] = v[i] * inv;
}

// ---------------------------------------------------------------------------
extern "C" void kernel_launch(void* const* d_in, const int* in_sizes, int n_in,
                              void* d_out, int out_size, void* d_ws, size_t ws_size,
                              hipStream_t stream) {
    const float* xv      = (const float*)d_in[0];
    const float* yv      = (const float*)d_in[1];
    const void*  xmask   = d_in[2];
    const int*   actions = (const int*)d_in[3];
    const float* weight  = (const float*)d_in[4];
    const float* cw0 = (const float*)d_in[5];
    const float* cb0 = (const float*)d_in[6];
    const float* cw1 = (const float*)d_in[7];
    const float* cb1 = (const float*)d_in[8];
    const float* cw2 = (const float*)d_in[9];
    const float* cb2 = (const float*)d_in[10];
    const float* cw3 = (const float*)d_in[11];
    const float* cb3 = (const float*)d_in[12];
    const float* cw4 = (const float*)d_in[13];
    const float* cb4 = (const float*)d_in[14];
    float* out = (float*)d_out;

    char* ws = (char*)d_ws;
    unsigned short* bufA = (unsigned short*)ws;                    // 33554432 B
    unsigned short* bufB = (unsigned short*)(ws + 33554432);       // 33554432 B
    char*  apack = ws + 67108864;                                  // 3 x 294912 B
    float* W_a   = (float*)(ws + 67993600);                        // 1048576 B
    float* Wy    = (float*)(ws + 69042176);                        // 32768 B
    int*   flag  = (int*)(ws + 69074944);

    // One packing launch for all 3 mid layers; block (0,0,0) clears flag.
    apack_all_kernel<<<dim3(9, 4, 3), 512, 0, stream>>>(cw1, cw2, cw3, apack, flag);
    detect_mask_kernel<<<32, 256, 0, stream>>>((const unsigned int*)xmask, flag);

    // Layer 0 fused into layer 1 (no act round-trip), then layers 2, 3.
    conv_mid_fused0<<<dim3(8, 32, 4), 256, 0, stream>>>(weight, cw0, cb0, apack, cb1, bufA);
    conv_mid_mfma<<<dim3(8, 32, 4), 256, 0, stream>>>(bufA, apack + 294912, cb2, bufB);
    conv_mid_mfma<<<dim3(8, 32, 4), 256, 0, stream>>>(bufB, apack + 589824, cb3, bufA);
    conv_last_kernel<<<dim3(256, 4), 256, 0, stream>>>(bufA, cw4, cb4, W_a);

    wy_kernel<<<32, 1024, 0, stream>>>(yv, actions, W_a, Wy);
    logits_kernel<<<dim3(8, 32), 256, 0, stream>>>(xv, xmask, flag, Wy, out);
    softmax_kernel<<<32, 1024, 0, stream>>>(out);
}

// Round 3
// 360.236 us; speedup vs baseline: 1.1143x; 1.1143x over previous
//
#include <hip/hip_runtime.h>
#include <cstdint>
#include <cstddef>

typedef __attribute__((ext_vector_type(8))) short bf16x8;
typedef __attribute__((ext_vector_type(4))) float f32x4;
typedef __attribute__((ext_vector_type(4))) int i32x4;

__device__ inline unsigned short cvt_bf16_rne(float f) {
    unsigned u = __builtin_bit_cast(unsigned, f);
    u = (u + 0x7FFFu + ((u >> 16) & 1u)) >> 16;
    return (unsigned short)u;
}
__device__ inline float bf16_to_f32(unsigned short s) {
    return __builtin_bit_cast(float, (unsigned)s << 16);
}

// ---------------------------------------------------------------------------
// Detect x_mask storage format: 0 = int32 {0,1}, 1 = bytes {0,1}, 2 = float32.
__global__ void detect_mask_kernel(const unsigned int* m, int* flag) {
    int i = blockIdx.x * blockDim.x + threadIdx.x;  // 8192 threads
    int f = 0;
    #pragma unroll
    for (int k = 0; k < 4; ++k) {
        unsigned int v = m[i * 4 + k];
        if (v == 0x3F800000u) f |= 2;
        else if (v > 1u) f |= 1;
    }
    if (f) atomicOr(flag, f);
}

// ---------------------------------------------------------------------------
// Pack mid-layer weights (layers 1..3) into MFMA A-fragment lane order (bf16).
// grid dim3(9, 4, 3) [tap, action, layer], 512 threads.
// Block (0,0,0) also clears the mask-format flag (detect runs after us).
__global__ void apack_all_kernel(const float* __restrict__ cw1,
                                 const float* __restrict__ cw2,
                                 const float* __restrict__ cw3,
                                 char* __restrict__ apack,
                                 int* __restrict__ flag) {
    int t = threadIdx.x;
    int tap = blockIdx.x, a = blockIdx.y, lz = blockIdx.z;
    if (tap == 0 && a == 0 && lz == 0 && t == 0) *flag = 0;
    const float* cw = (lz == 0) ? cw1 : (lz == 1 ? cw2 : cw3);
    char* outp = apack + (size_t)lz * 294912;
    int ks = t >> 8, mf = (t >> 6) & 3, lane = t & 63;
    int n = lane & 15, q = lane >> 4;
    int co = mf * 16 + n;
    int ci0 = ks * 32 + q * 8;
    unsigned d[4];
    #pragma unroll
    for (int jj = 0; jj < 4; ++jj) {
        unsigned short h0 = cvt_bf16_rne(cw[((size_t)(a * 64 + co) * 64 + ci0 + 2 * jj + 0) * 9 + tap]);
        unsigned short h1 = cvt_bf16_rne(cw[((size_t)(a * 64 + co) * 64 + ci0 + 2 * jj + 1) * 9 + tap]);
        d[jj] = (unsigned)h0 | ((unsigned)h1 << 16);
    }
    *(i32x4*)(outp + ((((size_t)(a * 9 + tap) * 2 + ks) * 4 + mf) * 1024 + lane * 16)) =
        *(i32x4*)d;
}

// ---------------------------------------------------------------------------
// Shared MFMA body for the mid layers: consumes the staged 10x34 halo tile in
// lds4, runs the 64->64 implicit GEMM, ReLU, stores bf16 act tile.
__device__ __forceinline__ void conv_mid_body(const i32x4* lds4,
                                              const char* __restrict__ apack_l,
                                              const float* __restrict__ cb,
                                              unsigned short* __restrict__ act_out,
                                              int a, int r0, int c0, int tid) {
    int lane = tid & 63, wv = tid >> 6;
    int n = lane & 15, q = lane >> 4;

    f32x4 acc[4][4];
    #pragma unroll
    for (int mf = 0; mf < 4; ++mf) {
        f32x4 bb = *(const f32x4*)(cb + a * 64 + mf * 16 + q * 4);
        #pragma unroll
        for (int nf = 0; nf < 4; ++nf) acc[mf][nf] = bb;
    }

    int base_nf[4];
    #pragma unroll
    for (int nf = 0; nf < 4; ++nf) {
        int orl = wv * 2 + (nf >> 1);
        int ocl = ((nf & 1) << 4) + n;
        base_nf[nf] = (orl * 34 + ocl) * 9 + q;  // i32x4 index at ty=tx=0,ks=0
    }
    const char* ap = apack_l + (size_t)a * 9 * 8192 + lane * 16;

    #pragma unroll
    for (int tap = 0; tap < 9; ++tap) {
        const int ty = tap / 3, tx = tap - ty * 3;
        const int toff = (ty * 34 + tx) * 9;
        #pragma unroll
        for (int ks = 0; ks < 2; ++ks) {
            bf16x8 Af[4], Bf[4];
            #pragma unroll
            for (int mf = 0; mf < 4; ++mf)
                Af[mf] = __builtin_bit_cast(bf16x8,
                    *(const i32x4*)(ap + (((tap * 2 + ks) * 4 + mf) << 10)));
            #pragma unroll
            for (int nf = 0; nf < 4; ++nf)
                Bf[nf] = __builtin_bit_cast(bf16x8, lds4[base_nf[nf] + toff + ks * 4]);
            #pragma unroll
            for (int mf = 0; mf < 4; ++mf)
                #pragma unroll
                for (int nf = 0; nf < 4; ++nf)
                    acc[mf][nf] = __builtin_amdgcn_mfma_f32_16x16x32_bf16(
                        Af[mf], Bf[nf], acc[mf][nf], 0, 0, 0);
        }
    }

    #pragma unroll
    for (int nf = 0; nf < 4; ++nf) {
        int grow = r0 + wv * 2 + (nf >> 1);
        int gcol = c0 + ((nf & 1) << 4) + n;
        char* ob = (char*)act_out + (((size_t)(a << 16) + (grow << 8) + gcol) << 7) + q * 8;
        #pragma unroll
        for (int mf = 0; mf < 4; ++mf) {
            f32x4 v = acc[mf][nf];
            unsigned d0 = (unsigned)cvt_bf16_rne(fmaxf(v.x, 0.0f))
                        | ((unsigned)cvt_bf16_rne(fmaxf(v.y, 0.0f)) << 16);
            unsigned d1 = (unsigned)cvt_bf16_rne(fmaxf(v.z, 0.0f))
                        | ((unsigned)cvt_bf16_rne(fmaxf(v.w, 0.0f)) << 16);
            uint2 st; st.x = d0; st.y = d1;
            *(uint2*)(ob + mf * 32) = st;
        }
    }
}

// ---------------------------------------------------------------------------
// Mid layers 2,3: stage bf16 act tile from global, then MFMA body.
// grid dim3(8, 32, 4), 256 threads.
__global__ __launch_bounds__(256, 3)
void conv_mid_mfma(const unsigned short* __restrict__ act_in,
                   const char* __restrict__ apack_l,
                   const float* __restrict__ cb,
                   unsigned short* __restrict__ act_out) {
    __shared__ i32x4 lds4[340 * 9];
    int tid = threadIdx.x;
    int a = blockIdx.z;
    int r0 = blockIdx.y * 8, c0 = blockIdx.x * 32;
    const char* actb = (const char*)act_in;

    for (int s = tid; s < 2720; s += 256) {
        int px = s >> 3, o = s & 7;
        int prow = px / 34, pcol = px - prow * 34;
        int grow = r0 - 1 + prow, gcol = c0 - 1 + pcol;
        i32x4 v = {0, 0, 0, 0};
        if ((unsigned)grow < 256u && (unsigned)gcol < 256u)
            v = *(const i32x4*)(actb + (((size_t)(a << 16) + (grow << 8) + gcol) << 7) + (o << 4));
        lds4[px * 9 + o] = v;
    }
    __syncthreads();
    conv_mid_body(lds4, apack_l, cb, act_out, a, r0, c0, tid);
}

// ---------------------------------------------------------------------------
// Layer 1 with layer 0 fused: stage a 12x36 fp32 img tile, compute the 1->64
// first conv + ReLU on the fly directly into lds4 (identical FMA order to the
// old conv_first_kernel => bit-identical), then the same MFMA body.
// grid dim3(8, 32, 4), 256 threads.
__global__ __launch_bounds__(256, 3)
void conv_mid_fused0(const float* __restrict__ img,
                     const float* __restrict__ cw0,
                     const float* __restrict__ cb0,
                     const char* __restrict__ apack_l,
                     const float* __restrict__ cb,
                     unsigned short* __restrict__ act_out) {
    __shared__ i32x4 lds4[340 * 9];
    __shared__ float img_s[12 * 36];
    int tid = threadIdx.x;
    int a = blockIdx.z;
    int r0 = blockIdx.y * 8, c0 = blockIdx.x * 32;

    for (int s = tid; s < 432; s += 256) {
        int ir = s / 36, ic = s - ir * 36;
        int gr = r0 - 2 + ir, gc = c0 - 2 + ic;
        img_s[s] = ((unsigned)gr < 256u && (unsigned)gc < 256u) ? img[gr * 256 + gc] : 0.0f;
    }
    __syncthreads();

    // Each thread keeps a fixed ci-octet o across its staging units.
    int o = tid & 7;
    float wr[8][9], br[8];
    #pragma unroll
    for (int j = 0; j < 8; ++j) {
        const float* wp = cw0 + ((size_t)a * 64 + o * 8 + j) * 9;
        #pragma unroll
        for (int t = 0; t < 9; ++t) wr[j][t] = wp[t];
        br[j] = cb0[a * 64 + o * 8 + j];
    }

    for (int s = tid; s < 2720; s += 256) {
        int px = s >> 3;
        int prow = px / 34, pcol = px - prow * 34;
        int grow = r0 - 1 + prow, gcol = c0 - 1 + pcol;
        i32x4 v = {0, 0, 0, 0};
        if ((unsigned)grow < 256u && (unsigned)gcol < 256u) {
            float accv[8];
            #pragma unroll
            for (int j = 0; j < 8; ++j) accv[j] = br[j];
            #pragma unroll
            for (int dy = 0; dy < 3; ++dy)
                #pragma unroll
                for (int dx = 0; dx < 3; ++dx) {
                    float iv = img_s[(prow + dy) * 36 + (pcol + dx)];
                    #pragma unroll
                    for (int j = 0; j < 8; ++j)
                        accv[j] = fmaf(wr[j][dy * 3 + dx], iv, accv[j]);
                }
            unsigned d[4];
            #pragma unroll
            for (int jj = 0; jj < 4; ++jj) {
                unsigned short h0 = cvt_bf16_rne(fmaxf(accv[2 * jj + 0], 0.0f));
                unsigned short h1 = cvt_bf16_rne(fmaxf(accv[2 * jj + 1], 0.0f));
                d[jj] = (unsigned)h0 | ((unsigned)h1 << 16);
            }
            v = *(i32x4*)d;
        }
        lds4[px * 9 + o] = v;
    }
    __syncthreads();
    conv_mid_body(lds4, apack_l, cb, act_out, a, r0, c0, tid);
}

// ---------------------------------------------------------------------------
// Layer 4: 64 -> 1, no ReLU, fp32 out W_a[a][256][256].
__global__ void conv_last_kernel(const unsigned short* __restrict__ act,
                                 const float* __restrict__ cw4,
                                 const float* __restrict__ cb4,
                                 float* __restrict__ W_a) {
    int y = blockIdx.x, a = blockIdx.y;
    int tid = threadIdx.x;
    int lane = tid & 63, wv = tid >> 6;
    int o = lane & 7, pl = lane >> 3;
    float wr[8][9];
    #pragma unroll
    for (int j = 0; j < 8; ++j) {
        const float* wp = cw4 + ((size_t)a * 64 + o * 8 + j) * 9;
        #pragma unroll
        for (int t = 0; t < 9; ++t) wr[j][t] = wp[t];
    }
    const char* actb = (const char*)act;
    float bias = cb4[a];
    for (int i = 0; i < 8; ++i) {
        int x = i * 32 + wv * 8 + pl;
        float p = 0.0f;
        #pragma unroll
        for (int ty = 0; ty < 3; ++ty) {
            int py = y + ty - 1;
            #pragma unroll
            for (int tx = 0; tx < 3; ++tx) {
                int px = x + tx - 1;
                if ((unsigned)py < 256u && (unsigned)px < 256u) {
                    i32x4 v = *(const i32x4*)(actb +
                        (((size_t)(a << 16) + (py << 8) + px) << 7) + (o << 4));
                    const unsigned* dv = (const unsigned*)&v;
                    #pragma unroll
                    for (int j = 0; j < 8; ++j) {
                        unsigned d = dv[j >> 1];
                        unsigned short us = (j & 1) ? (unsigned short)(d >> 16)
                                                    : (unsigned short)(d & 0xffffu);
                        p = fmaf(bf16_to_f32(us), wr[j][ty * 3 + tx], p);
                    }
                }
            }
        }
        p += __shfl_xor(p, 1, 64);
        p += __shfl_xor(p, 2, 64);
        p += __shfl_xor(p, 4, 64);
        if (o == 0) W_a[(size_t)(a << 16) + (y << 8) + x] = p + bias;
    }
}

// ---------------------------------------------------------------------------
// Wy[b,x] = sum_h y[b,h] * W_a[actions[b], h, x].
// 1024 threads: 4 partial-threads per x column (hq = t&3 handles h = i*4+hq),
// 4x shorter serial dependence than 1-thread-per-x; 2-shuffle finish.
__global__ void wy_kernel(const float* __restrict__ yv,
                          const int* __restrict__ actions,
                          const float* __restrict__ W_a,
                          float* __restrict__ Wy) {
    int b = blockIdx.x, t = threadIdx.x;
    int x = t >> 2, hq = t & 3;
    int a = actions[b];
    const float* Wp = W_a + (size_t)a * 65536;
    const float* yb = yv + b * 256;
    float acc = 0.0f;
    #pragma unroll 8
    for (int i = 0; i < 64; ++i) {
        int h = i * 4 + hq;
        acc = fmaf(yb[h], Wp[(size_t)h * 256 + x], acc);
    }
    acc += __shfl_xor(acc, 1, 64);
    acc += __shfl_xor(acc, 2, 64);
    if (hq == 0) Wy[b * 256 + x] = acc;
}

// ---------------------------------------------------------------------------
// Logits: 8 rows in flight per wave, all-register butterfly reduction.
// grid (64, 32), 256 threads (4 waves). Wave w handles 16 rows in 2 passes
// of 8; the 6 dependent shuffle steps have 8-wide ILP each; mask loads are
// hoisted to pass start (independent of the dot chain). No LDS, no syncs.
__global__ __launch_bounds__(256)
void logits_kernel(const float* __restrict__ xv,
                   const void* __restrict__ mask,
                   const int* __restrict__ flag,
                   const float* __restrict__ Wy,
                   float* __restrict__ out) {
    int tid = threadIdx.x, lane = tid & 63, w = tid >> 6;
    int b = blockIdx.y;
    int fl = *flag;
    float4 wy4 = *(const float4*)(Wy + b * 256 + lane * 4);
    const float* xb = xv + (size_t)b * 4096 * 256;
    float ninf = -__builtin_inff();
    int base0 = blockIdx.x * 64 + w * 16;

    #pragma unroll
    for (int it = 0; it < 2; ++it) {
        int base = base0 + it * 8;
        size_t mi = (size_t)b * 4096 + base;
        bool m[8];
        if (lane == 0) {
            if (fl & 2) {
                const float* mp = (const float*)mask + mi;
                #pragma unroll
                for (int j = 0; j < 8; ++j) m[j] = mp[j] != 0.0f;
            } else if (fl & 1) {
                const unsigned char* mp = (const unsigned char*)mask + mi;
                #pragma unroll
                for (int j = 0; j < 8; ++j) m[j] = mp[j] != 0;
            } else {
                const int* mp = (const int*)mask + mi;
                #pragma unroll
                for (int j = 0; j < 8; ++j) m[j] = mp[j] != 0;
            }
        }
        const float* rp = xb + (size_t)base * 256 + lane * 4;
        float p[8];
        #pragma unroll
        for (int j = 0; j < 8; ++j) {
            float4 x4 = *(const float4*)(rp + j * 256);
            p[j] = x4.x * wy4.x + x4.y * wy4.y + x4.z * wy4.z + x4.w * wy4.w;
        }
        #pragma unroll
        for (int off = 32; off > 0; off >>= 1)
            #pragma unroll
            for (int j = 0; j < 8; ++j)
                p[j] += __shfl_xor(p[j], off, 64);
        if (lane == 0) {
            #pragma unroll
            for (int j = 0; j < 8; ++j)
                out[mi + j] = m[j] ? ninf : p[j];
        }
    }
}

// ---------------------------------------------------------------------------
__global__ void softmax_kernel(float* __restrict__ out) {
    int b = blockIdx.x, tid = threadIdx.x;
    int lane = tid & 63, wid = tid >> 6;
    float* row = out + (size_t)b * 4096;
    float v[4];
    float m = -__builtin_inff();
    #pragma unroll
    for (int i = 0; i < 4; ++i) { v[i] = row[tid + i * 1024]; m = fmaxf(m, v[i]); }
    #pragma unroll
    for (int off = 32; off > 0; off >>= 1) m = fmaxf(m, __shfl_xor(m, off, 64));
    __shared__ float redm[16];
    __shared__ float reds[16];
    if (lane == 0) redm[wid] = m;
    __syncthreads();
    float M = redm[0];
    #pragma unroll
    for (int j = 1; j < 16; ++j) M = fmaxf(M, redm[j]);
    float s = 0.0f;
    #pragma unroll
    for (int i = 0; i < 4; ++i) { v[i] = expf(v[i] - M); s += v[i]; }
    #pragma unroll
    for (int off = 32; off > 0; off >>= 1) s += __shfl_xor(s, off, 64);
    if (lane == 0) reds[wid] = s;
    __syncthreads();
    float S = 0.0f;
    #pragma unroll
    for (int j = 0; j < 16; ++j) S += reds[j];
    float inv = 1.0f / S;
    #pragma unroll
    for (int i = 0; i < 4; ++i) row[tid + i * 1024] = v[i] * inv;
}

// ---------------------------------------------------------------------------
extern "C" void kernel_launch(void* const* d_in, const int* in_sizes, int n_in,
                              void* d_out, int out_size, void* d_ws, size_t ws_size,
                              hipStream_t stream) {
    const float* xv      = (const float*)d_in[0];
    const float* yv      = (const float*)d_in[1];
    const void*  xmask   = d_in[2];
    const int*   actions = (const int*)d_in[3];
    const float* weight  = (const float*)d_in[4];
    const float* cw0 = (const float*)d_in[5];
    const float* cb0 = (const float*)d_in[6];
    const float* cw1 = (const float*)d_in[7];
    const float* cb1 = (const float*)d_in[8];
    const float* cw2 = (const float*)d_in[9];
    const float* cb2 = (const float*)d_in[10];
    const float* cw3 = (const float*)d_in[11];
    const float* cb3 = (const float*)d_in[12];
    const float* cw4 = (const float*)d_in[13];
    const float* cb4 = (const float*)d_in[14];
    float* out = (float*)d_out;

    char* ws = (char*)d_ws;
    unsigned short* bufA = (unsigned short*)ws;                    // 33554432 B
    unsigned short* bufB = (unsigned short*)(ws + 33554432);       // 33554432 B
    char*  apack = ws + 67108864;                                  // 3 x 294912 B
    float* W_a   = (float*)(ws + 67993600);                        // 1048576 B
    float* Wy    = (float*)(ws + 69042176);                        // 32768 B
    int*   flag  = (int*)(ws + 69074944);

    // One packing launch for all 3 mid layers; block (0,0,0) clears flag.
    apack_all_kernel<<<dim3(9, 4, 3), 512, 0, stream>>>(cw1, cw2, cw3, apack, flag);
    detect_mask_kernel<<<32, 256, 0, stream>>>((const unsigned int*)xmask, flag);

    // Layer 0 fused into layer 1 (no act round-trip), then layers 2, 3.
    conv_mid_fused0<<<dim3(8, 32, 4), 256, 0, stream>>>(weight, cw0, cb0, apack, cb1, bufA);
    conv_mid_mfma<<<dim3(8, 32, 4), 256, 0, stream>>>(bufA, apack + 294912, cb2, bufB);
    conv_mid_mfma<<<dim3(8, 32, 4), 256, 0, stream>>>(bufB, apack + 589824, cb3, bufA);
    conv_last_kernel<<<dim3(256, 4), 256, 0, stream>>>(bufA, cw4, cb4, W_a);

    wy_kernel<<<32, 1024, 0, stream>>>(yv, actions, W_a, Wy);
    logits_kernel<<<dim3(64, 32), 256, 0, stream>>>(xv, xmask, flag, Wy, out);
    softmax_kernel<<<32, 1024, 0, stream>>>(out);
}

// Round 4
// 358.396 us; speedup vs baseline: 1.1200x; 1.0051x over previous
//
#include <hip/hip_runtime.h>
#include <cstdint>
#include <cstddef>

typedef __attribute__((ext_vector_type(8))) short bf16x8;
typedef __attribute__((ext_vector_type(4))) float f32x4;
typedef __attribute__((ext_vector_type(4))) int i32x4;

__device__ inline unsigned short cvt_bf16_rne(float f) {
    unsigned u = __builtin_bit_cast(unsigned, f);
    u = (u + 0x7FFFu + ((u >> 16) & 1u)) >> 16;
    return (unsigned short)u;
}
__device__ inline float bf16_to_f32(unsigned short s) {
    return __builtin_bit_cast(float, (unsigned)s << 16);
}

// ---------------------------------------------------------------------------
// Detect x_mask storage format: 0 = int32 {0,1}, 1 = bytes {0,1}, 2 = float32.
__global__ void detect_mask_kernel(const unsigned int* m, int* flag) {
    int i = blockIdx.x * blockDim.x + threadIdx.x;  // 8192 threads
    int f = 0;
    #pragma unroll
    for (int k = 0; k < 4; ++k) {
        unsigned int v = m[i * 4 + k];
        if (v == 0x3F800000u) f |= 2;
        else if (v > 1u) f |= 1;
    }
    if (f) atomicOr(flag, f);
}

// ---------------------------------------------------------------------------
// Pack mid-layer weights (layers 1..3) into MFMA A-fragment lane order (bf16).
// grid dim3(9, 4, 3) [tap, action, layer], 512 threads.
// Block (0,0,0) also clears the mask-format flag (detect runs after us).
__global__ void apack_all_kernel(const float* __restrict__ cw1,
                                 const float* __restrict__ cw2,
                                 const float* __restrict__ cw3,
                                 char* __restrict__ apack,
                                 int* __restrict__ flag) {
    int t = threadIdx.x;
    int tap = blockIdx.x, a = blockIdx.y, lz = blockIdx.z;
    if (tap == 0 && a == 0 && lz == 0 && t == 0) *flag = 0;
    const float* cw = (lz == 0) ? cw1 : (lz == 1 ? cw2 : cw3);
    char* outp = apack + (size_t)lz * 294912;
    int ks = t >> 8, mf = (t >> 6) & 3, lane = t & 63;
    int n = lane & 15, q = lane >> 4;
    int co = mf * 16 + n;
    int ci0 = ks * 32 + q * 8;
    unsigned d[4];
    #pragma unroll
    for (int jj = 0; jj < 4; ++jj) {
        unsigned short h0 = cvt_bf16_rne(cw[((size_t)(a * 64 + co) * 64 + ci0 + 2 * jj + 0) * 9 + tap]);
        unsigned short h1 = cvt_bf16_rne(cw[((size_t)(a * 64 + co) * 64 + ci0 + 2 * jj + 1) * 9 + tap]);
        d[jj] = (unsigned)h0 | ((unsigned)h1 << 16);
    }
    *(i32x4*)(outp + ((((size_t)(a * 9 + tap) * 2 + ks) * 4 + mf) * 1024 + lane * 16)) =
        *(i32x4*)d;
}

// ---------------------------------------------------------------------------
// Shared MFMA body for the mid layers: consumes the staged 10x34 halo tile in
// lds4, runs the 64->64 implicit GEMM, ReLU, stores bf16 act tile.
__device__ __forceinline__ void conv_mid_body(const i32x4* lds4,
                                              const char* __restrict__ apack_l,
                                              const float* __restrict__ cb,
                                              unsigned short* __restrict__ act_out,
                                              int a, int r0, int c0, int tid) {
    int lane = tid & 63, wv = tid >> 6;
    int n = lane & 15, q = lane >> 4;

    f32x4 acc[4][4];
    #pragma unroll
    for (int mf = 0; mf < 4; ++mf) {
        f32x4 bb = *(const f32x4*)(cb + a * 64 + mf * 16 + q * 4);
        #pragma unroll
        for (int nf = 0; nf < 4; ++nf) acc[mf][nf] = bb;
    }

    int base_nf[4];
    #pragma unroll
    for (int nf = 0; nf < 4; ++nf) {
        int orl = wv * 2 + (nf >> 1);
        int ocl = ((nf & 1) << 4) + n;
        base_nf[nf] = (orl * 34 + ocl) * 9 + q;  // i32x4 index at ty=tx=0,ks=0
    }
    const char* ap = apack_l + (size_t)a * 9 * 8192 + lane * 16;

    #pragma unroll
    for (int tap = 0; tap < 9; ++tap) {
        const int ty = tap / 3, tx = tap - ty * 3;
        const int toff = (ty * 34 + tx) * 9;
        #pragma unroll
        for (int ks = 0; ks < 2; ++ks) {
            bf16x8 Af[4], Bf[4];
            #pragma unroll
            for (int mf = 0; mf < 4; ++mf)
                Af[mf] = __builtin_bit_cast(bf16x8,
                    *(const i32x4*)(ap + (((tap * 2 + ks) * 4 + mf) << 10)));
            #pragma unroll
            for (int nf = 0; nf < 4; ++nf)
                Bf[nf] = __builtin_bit_cast(bf16x8, lds4[base_nf[nf] + toff + ks * 4]);
            #pragma unroll
            for (int mf = 0; mf < 4; ++mf)
                #pragma unroll
                for (int nf = 0; nf < 4; ++nf)
                    acc[mf][nf] = __builtin_amdgcn_mfma_f32_16x16x32_bf16(
                        Af[mf], Bf[nf], acc[mf][nf], 0, 0, 0);
        }
    }

    #pragma unroll
    for (int nf = 0; nf < 4; ++nf) {
        int grow = r0 + wv * 2 + (nf >> 1);
        int gcol = c0 + ((nf & 1) << 4) + n;
        char* ob = (char*)act_out + (((size_t)(a << 16) + (grow << 8) + gcol) << 7) + q * 8;
        #pragma unroll
        for (int mf = 0; mf < 4; ++mf) {
            f32x4 v = acc[mf][nf];
            unsigned d0 = (unsigned)cvt_bf16_rne(fmaxf(v.x, 0.0f))
                        | ((unsigned)cvt_bf16_rne(fmaxf(v.y, 0.0f)) << 16);
            unsigned d1 = (unsigned)cvt_bf16_rne(fmaxf(v.z, 0.0f))
                        | ((unsigned)cvt_bf16_rne(fmaxf(v.w, 0.0f)) << 16);
            uint2 st; st.x = d0; st.y = d1;
            *(uint2*)(ob + mf * 32) = st;
        }
    }
}

// ---------------------------------------------------------------------------
// Mid layers 2,3: stage bf16 act tile from global, then MFMA body.
// grid dim3(8, 32, 4), 256 threads.
__global__ __launch_bounds__(256, 3)
void conv_mid_mfma(const unsigned short* __restrict__ act_in,
                   const char* __restrict__ apack_l,
                   const float* __restrict__ cb,
                   unsigned short* __restrict__ act_out) {
    __shared__ i32x4 lds4[340 * 9];
    int tid = threadIdx.x;
    int a = blockIdx.z;
    int r0 = blockIdx.y * 8, c0 = blockIdx.x * 32;
    const char* actb = (const char*)act_in;

    for (int s = tid; s < 2720; s += 256) {
        int px = s >> 3, o = s & 7;
        int prow = px / 34, pcol = px - prow * 34;
        int grow = r0 - 1 + prow, gcol = c0 - 1 + pcol;
        i32x4 v = {0, 0, 0, 0};
        if ((unsigned)grow < 256u && (unsigned)gcol < 256u)
            v = *(const i32x4*)(actb + (((size_t)(a << 16) + (grow << 8) + gcol) << 7) + (o << 4));
        lds4[px * 9 + o] = v;
    }
    __syncthreads();
    conv_mid_body(lds4, apack_l, cb, act_out, a, r0, c0, tid);
}

// ---------------------------------------------------------------------------
// Layer 1 with layer 0 fused: stage a 12x36 fp32 img tile, compute the 1->64
// first conv + ReLU on the fly directly into lds4 (identical FMA order to the
// old conv_first_kernel => bit-identical), then the same MFMA body.
// grid dim3(8, 32, 4), 256 threads.
__global__ __launch_bounds__(256, 3)
void conv_mid_fused0(const float* __restrict__ img,
                     const float* __restrict__ cw0,
                     const float* __restrict__ cb0,
                     const char* __restrict__ apack_l,
                     const float* __restrict__ cb,
                     unsigned short* __restrict__ act_out) {
    __shared__ i32x4 lds4[340 * 9];
    __shared__ float img_s[12 * 36];
    int tid = threadIdx.x;
    int a = blockIdx.z;
    int r0 = blockIdx.y * 8, c0 = blockIdx.x * 32;

    for (int s = tid; s < 432; s += 256) {
        int ir = s / 36, ic = s - ir * 36;
        int gr = r0 - 2 + ir, gc = c0 - 2 + ic;
        img_s[s] = ((unsigned)gr < 256u && (unsigned)gc < 256u) ? img[gr * 256 + gc] : 0.0f;
    }
    __syncthreads();

    // Each thread keeps a fixed ci-octet o across its staging units.
    int o = tid & 7;
    float wr[8][9], br[8];
    #pragma unroll
    for (int j = 0; j < 8; ++j) {
        const float* wp = cw0 + ((size_t)a * 64 + o * 8 + j) * 9;
        #pragma unroll
        for (int t = 0; t < 9; ++t) wr[j][t] = wp[t];
        br[j] = cb0[a * 64 + o * 8 + j];
    }

    for (int s = tid; s < 2720; s += 256) {
        int px = s >> 3;
        int prow = px / 34, pcol = px - prow * 34;
        int grow = r0 - 1 + prow, gcol = c0 - 1 + pcol;
        i32x4 v = {0, 0, 0, 0};
        if ((unsigned)grow < 256u && (unsigned)gcol < 256u) {
            float accv[8];
            #pragma unroll
            for (int j = 0; j < 8; ++j) accv[j] = br[j];
            #pragma unroll
            for (int dy = 0; dy < 3; ++dy)
                #pragma unroll
                for (int dx = 0; dx < 3; ++dx) {
                    float iv = img_s[(prow + dy) * 36 + (pcol + dx)];
                    #pragma unroll
                    for (int j = 0; j < 8; ++j)
                        accv[j] = fmaf(wr[j][dy * 3 + dx], iv, accv[j]);
                }
            unsigned d[4];
            #pragma unroll
            for (int jj = 0; jj < 4; ++jj) {
                unsigned short h0 = cvt_bf16_rne(fmaxf(accv[2 * jj + 0], 0.0f));
                unsigned short h1 = cvt_bf16_rne(fmaxf(accv[2 * jj + 1], 0.0f));
                d[jj] = (unsigned)h0 | ((unsigned)h1 << 16);
            }
            v = *(i32x4*)d;
        }
        lds4[px * 9 + o] = v;
    }
    __syncthreads();
    conv_mid_body(lds4, apack_l, cb, act_out, a, r0, c0, tid);
}

// ---------------------------------------------------------------------------
// Layer 4: 64 -> 1, no ReLU, fp32 out W_a[a][256][256].
__global__ void conv_last_kernel(const unsigned short* __restrict__ act,
                                 const float* __restrict__ cw4,
                                 const float* __restrict__ cb4,
                                 float* __restrict__ W_a) {
    int y = blockIdx.x, a = blockIdx.y;
    int tid = threadIdx.x;
    int lane = tid & 63, wv = tid >> 6;
    int o = lane & 7, pl = lane >> 3;
    float wr[8][9];
    #pragma unroll
    for (int j = 0; j < 8; ++j) {
        const float* wp = cw4 + ((size_t)a * 64 + o * 8 + j) * 9;
        #pragma unroll
        for (int t = 0; t < 9; ++t) wr[j][t] = wp[t];
    }
    const char* actb = (const char*)act;
    float bias = cb4[a];
    for (int i = 0; i < 8; ++i) {
        int x = i * 32 + wv * 8 + pl;
        float p = 0.0f;
        #pragma unroll
        for (int ty = 0; ty < 3; ++ty) {
            int py = y + ty - 1;
            #pragma unroll
            for (int tx = 0; tx < 3; ++tx) {
                int px = x + tx - 1;
                if ((unsigned)py < 256u && (unsigned)px < 256u) {
                    i32x4 v = *(const i32x4*)(actb +
                        (((size_t)(a << 16) + (py << 8) + px) << 7) + (o << 4));
                    const unsigned* dv = (const unsigned*)&v;
                    #pragma unroll
                    for (int j = 0; j < 8; ++j) {
                        unsigned d = dv[j >> 1];
                        unsigned short us = (j & 1) ? (unsigned short)(d >> 16)
                                                    : (unsigned short)(d & 0xffffu);
                        p = fmaf(bf16_to_f32(us), wr[j][ty * 3 + tx], p);
                    }
                }
            }
        }
        p += __shfl_xor(p, 1, 64);
        p += __shfl_xor(p, 2, 64);
        p += __shfl_xor(p, 4, 64);
        if (o == 0) W_a[(size_t)(a << 16) + (y << 8) + x] = p + bias;
    }
}

// ---------------------------------------------------------------------------
// Wy[b,x] = sum_h y[b,h] * W_a[actions[b], h, x].
// 1024 threads: 4 partial-threads per x column (hq = t&3 handles h = i*4+hq),
// 4x shorter serial dependence than 1-thread-per-x; 2-shuffle finish.
__global__ void wy_kernel(const float* __restrict__ yv,
                          const int* __restrict__ actions,
                          const float* __restrict__ W_a,
                          float* __restrict__ Wy) {
    int b = blockIdx.x, t = threadIdx.x;
    int x = t >> 2, hq = t & 3;
    int a = actions[b];
    const float* Wp = W_a + (size_t)a * 65536;
    const float* yb = yv + b * 256;
    float acc = 0.0f;
    #pragma unroll 8
    for (int i = 0; i < 64; ++i) {
        int h = i * 4 + hq;
        acc = fmaf(yb[h], Wp[(size_t)h * 256 + x], acc);
    }
    acc += __shfl_xor(acc, 1, 64);
    acc += __shfl_xor(acc, 2, 64);
    if (hq == 0) Wy[b * 256 + x] = acc;
}

// ---------------------------------------------------------------------------
// Logits: 16 lanes per row (lane = r*16+i, 4 rows per wave-group).
// Lane i covers cols {i*4 + k*64}, k=0..3: each load instr is 4 dense 256B
// segments; 16 elements dotted in-register; reduce = 4 shfl_xor steps, all
// xor<16 (ds_swizzle-able), shared by 4 rows per instruction. ~1 DS op/row
// vs 6 in the butterfly version. grid (64, 32), 256 threads.
__global__ __launch_bounds__(256)
void logits_kernel(const float* __restrict__ xv,
                   const void* __restrict__ mask,
                   const int* __restrict__ flag,
                   const float* __restrict__ Wy,
                   float* __restrict__ out) {
    int tid = threadIdx.x, lane = tid & 63, w = tid >> 6;
    int i = lane & 15, r = lane >> 4;
    int b = blockIdx.y;
    int fl = *flag;
    float4 wyv[4];
    #pragma unroll
    for (int k = 0; k < 4; ++k)
        wyv[k] = *(const float4*)(Wy + b * 256 + k * 64 + i * 4);
    const float* xb = xv + (size_t)b * 4096 * 256;
    float ninf = -__builtin_inff();
    int base0 = blockIdx.x * 64 + w * 16;

    #pragma unroll 1
    for (int it = 0; it < 4; ++it) {
        int row = base0 + it * 4 + r;
        const float* rp = xb + (size_t)row * 256 + i * 4;
        float4 xq[4];
        #pragma unroll
        for (int k = 0; k < 4; ++k)
            xq[k] = *(const float4*)(rp + k * 64);
        float p = 0.0f;
        #pragma unroll
        for (int k = 0; k < 4; ++k) {
            p = fmaf(xq[k].x, wyv[k].x, p);
            p = fmaf(xq[k].y, wyv[k].y, p);
            p = fmaf(xq[k].z, wyv[k].z, p);
            p = fmaf(xq[k].w, wyv[k].w, p);
        }
        p += __shfl_xor(p, 8, 64);
        p += __shfl_xor(p, 4, 64);
        p += __shfl_xor(p, 2, 64);
        p += __shfl_xor(p, 1, 64);
        if (i == 0) {
            size_t mi = (size_t)b * 4096 + row;
            bool msk;
            if (fl & 2)      msk = ((const float*)mask)[mi] != 0.0f;
            else if (fl & 1) msk = ((const unsigned char*)mask)[mi] != 0;
            else             msk = ((const int*)mask)[mi] != 0;
            out[mi] = msk ? ninf : p;
        }
    }
}

// ---------------------------------------------------------------------------
__global__ void softmax_kernel(float* __restrict__ out) {
    int b = blockIdx.x, tid = threadIdx.x;
    int lane = tid & 63, wid = tid >> 6;
    float* row = out + (size_t)b * 4096;
    float v[4];
    float m = -__builtin_inff();
    #pragma unroll
    for (int i = 0; i < 4; ++i) { v[i] = row[tid + i * 1024]; m = fmaxf(m, v[i]); }
    #pragma unroll
    for (int off = 32; off > 0; off >>= 1) m = fmaxf(m, __shfl_xor(m, off, 64));
    __shared__ float redm[16];
    __shared__ float reds[16];
    if (lane == 0) redm[wid] = m;
    __syncthreads();
    float M = redm[0];
    #pragma unroll
    for (int j = 1; j < 16; ++j) M = fmaxf(M, redm[j]);
    float s = 0.0f;
    #pragma unroll
    for (int i = 0; i < 4; ++i) { v[i] = expf(v[i] - M); s += v[i]; }
    #pragma unroll
    for (int off = 32; off > 0; off >>= 1) s += __shfl_xor(s, off, 64);
    if (lane == 0) reds[wid] = s;
    __syncthreads();
    float S = 0.0f;
    #pragma unroll
    for (int j = 0; j < 16; ++j) S += reds[j];
    float inv = 1.0f / S;
    #pragma unroll
    for (int i = 0; i < 4; ++i) row[tid + i * 1024] = v[i] * inv;
}

// ---------------------------------------------------------------------------
extern "C" void kernel_launch(void* const* d_in, const int* in_sizes, int n_in,
                              void* d_out, int out_size, void* d_ws, size_t ws_size,
                              hipStream_t stream) {
    const float* xv      = (const float*)d_in[0];
    const float* yv      = (const float*)d_in[1];
    const void*  xmask   = d_in[2];
    const int*   actions = (const int*)d_in[3];
    const float* weight  = (const float*)d_in[4];
    const float* cw0 = (const float*)d_in[5];
    const float* cb0 = (const float*)d_in[6];
    const float* cw1 = (const float*)d_in[7];
    const float* cb1 = (const float*)d_in[8];
    const float* cw2 = (const float*)d_in[9];
    const float* cb2 = (const float*)d_in[10];
    const float* cw3 = (const float*)d_in[11];
    const float* cb3 = (const float*)d_in[12];
    const float* cw4 = (const float*)d_in[13];
    const float* cb4 = (const float*)d_in[14];
    float* out = (float*)d_out;

    char* ws = (char*)d_ws;
    unsigned short* bufA = (unsigned short*)ws;                    // 33554432 B
    unsigned short* bufB = (unsigned short*)(ws + 33554432);       // 33554432 B
    char*  apack = ws + 67108864;                                  // 3 x 294912 B
    float* W_a   = (float*)(ws + 67993600);                        // 1048576 B
    float* Wy    = (float*)(ws + 69042176);                        // 32768 B
    int*   flag  = (int*)(ws + 69074944);

    // One packing launch for all 3 mid layers; block (0,0,0) clears flag.
    apack_all_kernel<<<dim3(9, 4, 3), 512, 0, stream>>>(cw1, cw2, cw3, apack, flag);
    detect_mask_kernel<<<32, 256, 0, stream>>>((const unsigned int*)xmask, flag);

    // Layer 0 fused into layer 1 (no act round-trip), then layers 2, 3.
    conv_mid_fused0<<<dim3(8, 32, 4), 256, 0, stream>>>(weight, cw0, cb0, apack, cb1, bufA);
    conv_mid_mfma<<<dim3(8, 32, 4), 256, 0, stream>>>(bufA, apack + 294912, cb2, bufB);
    conv_mid_mfma<<<dim3(8, 32, 4), 256, 0, stream>>>(bufB, apack + 589824, cb3, bufA);
    conv_last_kernel<<<dim3(256, 4), 256, 0, stream>>>(bufA, cw4, cb4, W_a);

    wy_kernel<<<32, 1024, 0, stream>>>(yv, actions, W_a, Wy);
    logits_kernel<<<dim3(64, 32), 256, 0, stream>>>(xv, xmask, flag, Wy, out);
    softmax_kernel<<<32, 1024, 0, stream>>>(out);
}